// Round 8
// baseline (112.629 us; speedup 1.0000x reference)
//
#include <hip/hip_runtime.h>
#include <stdint.h>

// ============================================================================
// LaneGraphConvLayerShared: NNConv(edge-conditioned) + root + residual + LN
//
// msg[e] = sum_{s<16} a[e,s]*(x[src]@W_s) + x[src]@Bb   (Bb = reshape(b_edge))
//
// R7 post-mortem: 4 different compute schedules all pin at 63-71us with the
//   SAME scatter (9.6M f32 atomics to random out rows). out lines ping-pong
//   across non-coherent per-XCD L2s (WRITE ~= 3x out size ~ avg degree).
//   The wall is scatter locality, not compute.
// R8: device counting-sort edges by dst (hist + 3-kernel scan + place, ~1MB
//   ws), then tiles process dst-contiguous edges: per-tile SEGMENT reduction
//   in LDS -> one coalesced atomic wave-instr per segment (3x fewer atomics),
//   plus m204-bijective XCD-chunked tile mapping so adjacent dst ranges stay
//   in one XCD's L2. Compute core = R7 (f-col split, per-slot y + f32
//   a-scale). launch_bounds(256,3) caps VGPR at 168 (live ~120, no spill).
// ============================================================================

#define PREP_ELEMS 69632
#define PREP_BLOCKS 272  // ceil(69632/256)

typedef short short8 __attribute__((ext_vector_type(8)));
typedef float floatx4 __attribute__((ext_vector_type(4)));

__device__ __forceinline__ uint32_t cvt_pk_bf16(float lo, float hi) {
  uint32_t r;
  asm("v_cvt_pk_bf16_f32 %0, %1, %2" : "=v"(r) : "v"(lo), "v"(hi));
  return r;
}

__device__ __forceinline__ uint16_t f32_to_bf16_bits(float x) {
  uint32_t u = __float_as_uint(x);
  u += 0x7fffu + ((u >> 16) & 1u);
  return (uint16_t)(u >> 16);
}

__device__ __forceinline__ float f4_get(const float4& v, int i) {
  return i == 0 ? v.x : i == 1 ? v.y : i == 2 ? v.z : v.w;
}

// K1: [0,PREP_BLOCKS) build w2frag; [PREP_BLOCKS,+nBase) base GEMM;
//     [+nBase, +nHist) histogram of dst into cnt (cnt pre-zeroed).
__global__ __launch_bounds__(256) void k1_kernel(
    const float* __restrict__ x,
    const float* __restrict__ W_edge, const float* __restrict__ b_edge,
    const float* __restrict__ W_root, const float* __restrict__ bias,
    const float* __restrict__ W_res,  const float* __restrict__ b_res,
    const int* __restrict__ dstp, int* __restrict__ cnt,
    uint16_t* __restrict__ w2frag, float* __restrict__ out,
    int N, int E, int nBase) {
  int tid = threadIdx.x;
  if (blockIdx.x < PREP_BLOCKS) {
    int gid = blockIdx.x * 256 + tid;
    if (gid < PREP_ELEMS) {
      int i = gid & 7, l = (gid >> 3) & 63, c = (gid >> 9) & 3;
      int t = (gid >> 11) & 1, s = gid >> 12;
      int d = t * 32 + 8 * (l >> 4) + i;
      int f = c * 16 + (l & 15);
      float v = (s < 16) ? W_edge[s * 4096 + d * 64 + f] : b_edge[d * 64 + f];
      w2frag[gid] = f32_to_bf16_bits(v);
    }
    return;
  }
  if (blockIdx.x >= PREP_BLOCKS + nBase) {
    int gid = (blockIdx.x - PREP_BLOCKS - nBase) * 256 + tid;
    if (gid < E) atomicAdd(&cnt[dstp[gid]], 1);
    return;
  }
  int bb = blockIdx.x - PREP_BLOCKS;
  int w = tid >> 6, l = tid & 63, l16 = l & 15, lq = l >> 4;
  union BF { short8 s8; uint16_t h[8]; } Bf[2][4];
#pragma unroll
  for (int t = 0; t < 2; ++t)
#pragma unroll
    for (int c = 0; c < 4; ++c)
#pragma unroll
      for (int i = 0; i < 8; ++i) {
        int d = t * 32 + 8 * lq + i;
        int f = c * 16 + l16;
        Bf[t][c].h[i] = f32_to_bf16_bits(W_root[d * 64 + f] + W_res[d * 64 + f]);
      }
  int arow = bb * 64 + w * 16 + l16;
  float xv[16];
#pragma unroll
  for (int t = 0; t < 2; ++t)
#pragma unroll
    for (int i = 0; i < 8; ++i)
      xv[t * 8 + i] = (arow < N) ? x[arow * 64 + t * 32 + 8 * lq + i] : 0.0f;
  union { short8 s8; uint32_t u[4]; } A[2];
#pragma unroll
  for (int t = 0; t < 2; ++t)
#pragma unroll
    for (int j = 0; j < 4; ++j)
      A[t].u[j] = cvt_pk_bf16(xv[t * 8 + 2 * j], xv[t * 8 + 2 * j + 1]);
  floatx4 acc[4];
#pragma unroll
  for (int c = 0; c < 4; ++c) acc[c] = (floatx4){0.f, 0.f, 0.f, 0.f};
#pragma unroll
  for (int t = 0; t < 2; ++t)
#pragma unroll
    for (int c = 0; c < 4; ++c)
      acc[c] = __builtin_amdgcn_mfma_f32_16x16x32_bf16(A[t].s8, Bf[t][c].s8, acc[c], 0, 0, 0);
#pragma unroll
  for (int c = 0; c < 4; ++c) {
    int f = c * 16 + l16;
    float bs = bias[f] + b_res[f];
#pragma unroll
    for (int r = 0; r < 4; ++r) {
      int row = bb * 64 + w * 16 + lq * 4 + r;
      if (row < N) out[row * 64 + f] = acc[c][r] + bs;
    }
  }
}

// block-local exclusive scan of cnt -> off, chunk totals -> bsum
__global__ __launch_bounds__(256) void scan_a(const int* __restrict__ cnt,
                                              int* __restrict__ off,
                                              int* __restrict__ bsum, int N) {
  int tid = threadIdx.x, gid = blockIdx.x * 256 + tid;
  int l = tid & 63, w = tid >> 6;
  int v = (gid < N) ? cnt[gid] : 0;
  int s = v;
#pragma unroll
  for (int d = 1; d < 64; d <<= 1) {
    int t = __shfl_up(s, d);
    if (l >= d) s += t;
  }
  __shared__ int wt[4];
  if (l == 63) wt[w] = s;
  __syncthreads();
  int add = 0;
  for (int i = 0; i < w; ++i) add += wt[i];
  s += add;
  if (gid < N) off[gid] = s - v;
  if (tid == 255) bsum[blockIdx.x] = s;
}

// single-block exclusive scan of bsum[NB] (NB <= 256)
__global__ __launch_bounds__(256) void scan_b(int* __restrict__ bsum, int NB) {
  int tid = threadIdx.x, l = tid & 63, w = tid >> 6;
  int v = (tid < NB) ? bsum[tid] : 0;
  int s = v;
#pragma unroll
  for (int d = 1; d < 64; d <<= 1) {
    int t = __shfl_up(s, d);
    if (l >= d) s += t;
  }
  __shared__ int wt[4];
  if (l == 63) wt[w] = s;
  __syncthreads();
  int add = 0;
  for (int i = 0; i < w; ++i) add += wt[i];
  s += add;
  if (tid < NB) bsum[tid] = s - v;
}

// cursor = off + chunk offset (final exclusive prefix of counts)
__global__ __launch_bounds__(256) void scan_c(const int* __restrict__ off,
                                              const int* __restrict__ bsum,
                                              int* __restrict__ cursor, int N) {
  int gid = blockIdx.x * 256 + threadIdx.x;
  if (gid < N) cursor[gid] = off[gid] + bsum[blockIdx.x];
}

// place: eord[cursor[dst[e]]++] = e
__global__ __launch_bounds__(256) void place_kernel(const int* __restrict__ dstp,
                                                    int* __restrict__ cursor,
                                                    int* __restrict__ eord, int E) {
  int gid = blockIdx.x * 256 + threadIdx.x;
  if (gid < E) {
    int pos = atomicAdd(&cursor[dstp[gid]], 1);
    eord[pos] = gid;
  }
}

// edge: 64 dst-sorted edges per tile; R7 compute core; LDS segment reduction;
// one coalesced atomic wave-instr per (segment). XCD-chunked tile mapping.
__global__ __launch_bounds__(256, 3) void edge_kernel(
    const float* __restrict__ x, const int* __restrict__ eidx,
    const float* __restrict__ attr, const uint16_t* __restrict__ w2frag,
    const int* __restrict__ eord, float* __restrict__ out, int E, int T) {
  __shared__ __align__(16) uint16_t xb[64 * 64];  // bf16, swizzled, 8KB
  __shared__ __align__(16) float a_lds[64][20];
  __shared__ int dst_lds[64];
  __shared__ float red[64][68];

  int tid = threadIdx.x;
  int w = tid >> 6, l = tid & 63, l16 = l & 15, lq = l >> 4;

  // m204 bijective XCD-chunk: XCD k gets a contiguous tile range
  int q8 = T >> 3, r8 = T & 7;
  int xcd = blockIdx.x & 7, idx = blockIdx.x >> 3;
  int tl = (xcd < r8 ? xcd * (q8 + 1) : r8 * (q8 + 1) + (xcd - r8) * q8) + idx;
  int tile0 = tl * 64;
  int cnt = min(64, E - tile0);
  const int* srcp = eidx;
  const int* dstp = eidx + E;

  // ---- stage x (bf16, XOR-swizzled), a, dst via sorted edge ids ----
  {
    int row = tid >> 2, q = tid & 3;
    bool ok = row < cnt;
    int e = eord[tile0 + (ok ? row : 0)];
    int sidx = srcp[e];
    const float4* xs = (const float4*)(x + sidx * 64);
    float4 v[4];
#pragma unroll
    for (int j = 0; j < 4; ++j) v[j] = xs[q * 4 + j];
    uint4 c0, c1;
    c0.x = cvt_pk_bf16(v[0].x, v[0].y);
    c0.y = cvt_pk_bf16(v[0].z, v[0].w);
    c0.z = cvt_pk_bf16(v[1].x, v[1].y);
    c0.w = cvt_pk_bf16(v[1].z, v[1].w);
    c1.x = cvt_pk_bf16(v[2].x, v[2].y);
    c1.y = cvt_pk_bf16(v[2].z, v[2].w);
    c1.z = cvt_pk_bf16(v[3].x, v[3].y);
    c1.w = cvt_pk_bf16(v[3].z, v[3].w);
    int swz = (row & 7) << 4;
    *(uint4*)((char*)xb + ((row * 128 + q * 32) ^ swz)) = c0;
    *(uint4*)((char*)xb + ((row * 128 + q * 32 + 16) ^ swz)) = c1;
    *(float4*)&a_lds[row][q * 4] = ((const float4*)attr)[e * 4 + q];
    if (q == 0) dst_lds[row] = dstp[e];
  }
  __syncthreads();

  // ---- A-frags once per tile (swizzled, conflict-free) ----
  short8 A[4][2];
  int swzr = (l16 & 7) << 4;
#pragma unroll
  for (int rt = 0; rt < 4; ++rt) {
    int rb = (rt * 16 + l16) * 128;
    A[rt][0] = *(const short8*)((const char*)xb + ((rb + lq * 16) ^ swzr));
    A[rt][1] = *(const short8*)((const char*)xb + ((rb + 64 + lq * 16) ^ swzr));
  }

  floatx4 acc[4];
#pragma unroll
  for (int rt = 0; rt < 4; ++rt) acc[rt] = (floatx4){0.f, 0.f, 0.f, 0.f};

  const short8* bp = (const short8*)w2frag;
  short8 Bb0 = bp[(32 * 4 + w) * 64 + l];
  short8 Bb1 = bp[(33 * 4 + w) * 64 + l];

#pragma unroll
  for (int g = 0; g < 4; ++g) {
    short8 Bf[8];
#pragma unroll
    for (int sg = 0; sg < 4; ++sg) {
      int s = g * 4 + sg;
      Bf[sg * 2 + 0] = bp[((s * 2 + 0) * 4 + w) * 64 + l];
      Bf[sg * 2 + 1] = bp[((s * 2 + 1) * 4 + w) * 64 + l];
    }
#pragma unroll
    for (int rt = 0; rt < 4; ++rt) {
      float4 av[4];
#pragma unroll
      for (int r = 0; r < 4; ++r)
        av[r] = *(const float4*)&a_lds[rt * 16 + lq * 4 + r][g * 4];
#pragma unroll
      for (int sg = 0; sg < 4; ++sg) {
        floatx4 y = (floatx4){0.f, 0.f, 0.f, 0.f};
        y = __builtin_amdgcn_mfma_f32_16x16x32_bf16(A[rt][0], Bf[sg * 2 + 0], y, 0, 0, 0);
        y = __builtin_amdgcn_mfma_f32_16x16x32_bf16(A[rt][1], Bf[sg * 2 + 1], y, 0, 0, 0);
        acc[rt][0] += f4_get(av[0], sg) * y[0];
        acc[rt][1] += f4_get(av[1], sg) * y[1];
        acc[rt][2] += f4_get(av[2], sg) * y[2];
        acc[rt][3] += f4_get(av[3], sg) * y[3];
      }
    }
  }
#pragma unroll
  for (int rt = 0; rt < 4; ++rt) {
    floatx4 y = (floatx4){0.f, 0.f, 0.f, 0.f};
    y = __builtin_amdgcn_mfma_f32_16x16x32_bf16(A[rt][0], Bb0, y, 0, 0, 0);
    y = __builtin_amdgcn_mfma_f32_16x16x32_bf16(A[rt][1], Bb1, y, 0, 0, 0);
    acc[rt] += y;
  }

  // ---- acc -> red (2-way bank alias only, pad 68) ----
#pragma unroll
  for (int rt = 0; rt < 4; ++rt)
#pragma unroll
    for (int r = 0; r < 4; ++r)
      red[rt * 16 + lq * 4 + r][w * 16 + l16] = acc[rt][r];
  __syncthreads();

  // ---- segment reduce + coalesced atomic: wave w scans heads in its 16 rows,
  //      lane l = f. dst_lds is sorted; branches are wave-uniform. ----
  int i1 = min(w * 16 + 16, cnt);
  for (int i = w * 16; i < i1; ++i) {
    int d = dst_lds[i];
    if (i > 0 && dst_lds[i - 1] == d) continue;  // head is in an earlier run
    float s = red[i][l];
    int j = i + 1;
    while (j < cnt && dst_lds[j] == d) { s += red[j][l]; ++j; }
    atomicAdd(&out[d * 64 + l], s);
  }
}

__global__ __launch_bounds__(256) void ln_kernel(
    float* __restrict__ out, const float* __restrict__ gamma,
    const float* __restrict__ beta, int N) {
  int w = threadIdx.x >> 6, l = threadIdx.x & 63;
  int row = blockIdx.x * 4 + w;
  if (row >= N) return;
  float v = out[row * 64 + l];
  float s = v;
#pragma unroll
  for (int m = 32; m >= 1; m >>= 1) s += __shfl_xor(s, m);
  float mu = s * 0.015625f;
  float d = v - mu;
  float q = d * d;
#pragma unroll
  for (int m = 32; m >= 1; m >>= 1) q += __shfl_xor(q, m);
  float var = q * 0.015625f;
  out[row * 64 + l] = d * rsqrtf(var + 1e-5f) * gamma[l] + beta[l];
}

extern "C" void kernel_launch(void* const* d_in, const int* in_sizes, int n_in,
                              void* d_out, int out_size, void* d_ws, size_t ws_size,
                              hipStream_t stream) {
  const float* x      = (const float*)d_in[0];
  const int*   eidx   = (const int*)d_in[1];
  const float* attr   = (const float*)d_in[2];
  const float* W_edge = (const float*)d_in[3];
  const float* b_edge = (const float*)d_in[4];
  const float* W_root = (const float*)d_in[5];
  const float* bias   = (const float*)d_in[6];
  const float* W_res  = (const float*)d_in[7];
  const float* b_res  = (const float*)d_in[8];
  const float* gamma  = (const float*)d_in[9];
  const float* beta   = (const float*)d_in[10];
  int N = in_sizes[0] / 64;
  int E = in_sizes[1] / 2;
  float* out = (float*)d_out;

  // ws layout
  size_t o = 0;
  uint16_t* w2frag = (uint16_t*)((char*)d_ws + o); o += 139776;          // 69632*2, padded
  int* cnt    = (int*)((char*)d_ws + o); o += ((size_t)N * 4 + 511) & ~511ull;  // -> cursor
  int* off    = (int*)((char*)d_ws + o); o += ((size_t)N * 4 + 511) & ~511ull;
  int* bsum   = (int*)((char*)d_ws + o); o += 1024;
  int* eord   = (int*)((char*)d_ws + o); o += ((size_t)E * 4 + 511) & ~511ull;

  const int* dstp = eidx + E;
  int nBase = (N + 63) / 64;
  int nHist = (E + 255) / 256;
  int nScan = (N + 255) / 256;

  hipMemsetAsync(cnt, 0, (size_t)N * 4, stream);
  k1_kernel<<<PREP_BLOCKS + nBase + nHist, 256, 0, stream>>>(
      x, W_edge, b_edge, W_root, bias, W_res, b_res, dstp, cnt, w2frag, out,
      N, E, nBase);
  scan_a<<<nScan, 256, 0, stream>>>(cnt, off, bsum, N);
  scan_b<<<1, 256, 0, stream>>>(bsum, nScan);
  scan_c<<<nScan, 256, 0, stream>>>(off, bsum, cnt, N);  // cnt becomes cursor
  place_kernel<<<nHist, 256, 0, stream>>>(dstp, cnt, eord, E);
  int T = (E + 63) / 64;
  edge_kernel<<<T, 256, 0, stream>>>(x, eidx, attr, w2frag, eord, out, E, T);
  ln_kernel<<<(N + 3) / 4, 256, 0, stream>>>(out, gamma, beta, N);
}